// Round 3
// baseline (338.363 us; speedup 1.0000x reference)
//
#include <hip/hip_runtime.h>

#define HEADS 16
#define NQ    2048
#define NKV   4096
#define DH    128
#define PDIM  64

typedef __bf16 bf16_t;
typedef bf16_t bf16x8 __attribute__((ext_vector_type(8)));
typedef bf16_t bf16x4 __attribute__((ext_vector_type(4)));
typedef float  f32x4  __attribute__((ext_vector_type(4)));

// ---------------------------------------------------------------------------
// proj: rows 0..32767 are Q (scaled by (1/8)*log2e), rows 32768.. are K.
// Epilogue goes through wave-private LDS so global stores are b128-coalesced.
// ---------------------------------------------------------------------------
__global__ __launch_bounds__(256) void proj_kernel(
    const float* __restrict__ Q, const float* __restrict__ K,
    const float* __restrict__ R, bf16_t* __restrict__ Qp, bf16_t* __restrict__ Kp)
{
  __shared__ bf16_t sY[4][16 * 72];
  const int tid  = threadIdx.x;
  const int wave = tid >> 6, lane = tid & 63;
  const int n16  = lane & 15, quad = lane >> 4;

  // B fragments from R: B[k][n], n = nt*16+n16, k = kk*32 + quad*8 + j
  bf16x8 bfr[4][4];
#pragma unroll
  for (int nt = 0; nt < 4; ++nt) {
    const int n = nt * 16 + n16;
#pragma unroll
    for (int kk = 0; kk < 4; ++kk) {
      const int k0 = kk * 32 + quad * 8;
      bf16x8 b;
#pragma unroll
      for (int j = 0; j < 8; ++j) b[j] = (bf16_t)R[(k0 + j) * PDIM + n];
      bfr[nt][kk] = b;
    }
  }

  const long rowblock = (long)blockIdx.x * 256 + wave * 64;
  const long qrows = (long)HEADS * NQ;

#pragma unroll 1
  for (int t = 0; t < 4; ++t) {
    const long r0 = rowblock + t * 16;
    const float* X; bf16_t* Y; float scale; long xrow;
    if (r0 < qrows) { X = Q; Y = Qp; scale = 0.18033688011112042f; xrow = r0; }   // (1/8)*log2(e)
    else            { X = K; Y = Kp; scale = 1.0f;                 xrow = r0 - qrows; }

    const float* xp = X + (xrow + n16) * DH;
    bf16x8 a[4];
#pragma unroll
    for (int kk = 0; kk < 4; ++kk) {
      const int k0 = kk * 32 + quad * 8;
      f32x4 x0 = *(const f32x4*)(xp + k0);
      f32x4 x1 = *(const f32x4*)(xp + k0 + 4);
      bf16x8 av;
#pragma unroll
      for (int j = 0; j < 4; ++j) { av[j] = (bf16_t)(x0[j] * scale); av[4 + j] = (bf16_t)(x1[j] * scale); }
      a[kk] = av;
    }
    bf16_t* sy = sY[wave];
#pragma unroll
    for (int nt = 0; nt < 4; ++nt) {
      f32x4 acc = {0.f, 0.f, 0.f, 0.f};
#pragma unroll
      for (int kk = 0; kk < 4; ++kk)
        acc = __builtin_amdgcn_mfma_f32_16x16x32_bf16(a[kk], bfr[nt][kk], acc, 0, 0, 0);
#pragma unroll
      for (int r = 0; r < 4; ++r)
        sy[(quad * 4 + r) * 72 + nt * 16 + n16] = (bf16_t)acc[r];
    }
    // coalesced store: lane -> (row = lane>>2, colgroup = lane&3), 1 KB/instr
    const int row = lane >> 2, cg = lane & 3;
    bf16x8 w0 = *(const bf16x8*)(&sy[row * 72 + cg * 16]);
    bf16x8 w1 = *(const bf16x8*)(&sy[row * 72 + cg * 16 + 8]);
    *(bf16x8*)(Y + (xrow + row) * PDIM + cg * 16)     = w0;
    *(bf16x8*)(Y + (xrow + row) * PDIM + cg * 16 + 8) = w1;
  }
}

// ---------------------------------------------------------------------------
// V [H][NKV][128] fp32  ->  Vt [H][128][NKV] bf16 (transpose via padded LDS)
// ---------------------------------------------------------------------------
__global__ __launch_bounds__(256) void vtrans_kernel(
    const float* __restrict__ V, bf16_t* __restrict__ Vt)
{
  __shared__ float sF[64 * 129];
  const int tid = threadIdx.x;
  const int h = blockIdx.y, jt = blockIdx.x;
  const float* vp = V + ((long)h * NKV + jt * 64) * DH;
#pragma unroll
  for (int rep = 0; rep < 8; ++rep) {
    const int slot = tid + rep * 256;
    const int j = slot >> 5, c4 = (slot & 31) * 4;
    f32x4 v = *(const f32x4*)(vp + j * DH + c4);
    float* dst = &sF[j * 129 + c4];
    dst[0] = v[0]; dst[1] = v[1]; dst[2] = v[2]; dst[3] = v[3];
  }
  __syncthreads();
  bf16_t* op = Vt + (long)h * DH * NKV + jt * 64;
#pragma unroll
  for (int rep = 0; rep < 4; ++rep) {
    const int slot = tid + rep * 256;
    const int d = slot >> 3, j8 = (slot & 7) * 8;
    bf16x8 w;
#pragma unroll
    for (int jj = 0; jj < 8; ++jj) w[jj] = (bf16_t)sF[(j8 + jj) * 129 + d];
    *(bf16x8*)(op + (long)d * NKV + j8) = w;
  }
}

// ---------------------------------------------------------------------------
// flash v3: transposed orientation. S^T = K.Q^T so Q lives in registers as
// the B operand and P exits with kv contiguous per lane (b64 packed writes,
// per-lane row sums, zero in-loop shuffles). Wave owns 64 q-rows; block =
// 2 waves = 128 q-rows. KV-split (additive under fixed-max softmax) gives
// grid = 1024 blocks -> 3 blocks/CU (45 KB LDS), 6 waves/CU.
// ---------------------------------------------------------------------------
__global__ __launch_bounds__(128, 2) void flash_kernel(
    const bf16_t* __restrict__ Qp, const bf16_t* __restrict__ Kp,
    const bf16_t* __restrict__ Vt, bf16_t* __restrict__ Opart,
    float* __restrict__ Lpart, float* __restrict__ Out,
    int splits, int iters)
{
  const int tid  = threadIdx.x;
  const int wave = tid >> 6, lane = tid & 63;
  const int n16  = lane & 15, quad = lane >> 4;

  const int h  = blockIdx.x & 15;          // XCD round-robin for K/V L2 locality
  const int qt = (blockIdx.x >> 4) & 15;
  const int sp = blockIdx.x >> 8;          // kv-split index (0 when splits==1)

  const int qbase = qt * 128 + wave * 64;
  const int kv0   = sp * (64 * iters);

  __shared__ bf16_t sK[64 * 72];
  __shared__ bf16_t sV[128 * 72];
  __shared__ bf16_t sP[2][64 * 72];

  // persistent Q B-frags: B[k=p][n=q], n = n16 (+16*g), k = quad*8+j (+32*kc)
  bf16x8 qf[4][2];
#pragma unroll
  for (int g = 0; g < 4; ++g) {
    const bf16_t* qr = Qp + ((long)h * NQ + qbase + g * 16 + n16) * PDIM;
    qf[g][0] = *(const bf16x8*)(qr + quad * 8);
    qf[g][1] = *(const bf16x8*)(qr + 32 + quad * 8);
  }

  f32x4 o[4][8];
  float rsum[4];
  const f32x4 zero = {0.f, 0.f, 0.f, 0.f};
#pragma unroll
  for (int g = 0; g < 4; ++g) {
    rsum[g] = 0.f;
#pragma unroll
    for (int d = 0; d < 8; ++d) o[g][d] = zero;
  }

  const bf16_t* kpH = Kp + (long)h * NKV * PDIM;
  const bf16_t* vtH = Vt + (long)h * DH * NKV;
  bf16_t* pw = sP[wave];

  for (int t = 0; t < iters; ++t) {
    __syncthreads();
    {
      const bf16_t* src = kpH + (long)(kv0 + t * 64) * PDIM;
#pragma unroll
      for (int rep = 0; rep < 4; ++rep) {
        const int slot = tid + rep * 128;
        const int row = slot >> 3, c8 = (slot & 7) * 8;
        *(bf16x8*)(&sK[row * 72 + c8]) = *(const bf16x8*)(src + row * 64 + c8);
      }
      const bf16_t* vsrc = vtH + kv0 + t * 64;
#pragma unroll
      for (int rep = 0; rep < 8; ++rep) {
        const int slot = tid + rep * 128;
        const int row = slot >> 3, c8 = (slot & 7) * 8;
        *(bf16x8*)(&sV[row * 72 + c8]) = *(const bf16x8*)(vsrc + (long)row * NKV + c8);
      }
    }
    __syncthreads();

    // S^T[kv 64][q 64]: A = K-tile rows (kv), B = Q frags. Log2 domain.
#pragma unroll
    for (int mt = 0; mt < 4; ++mt) {
      const bf16_t* ka = &sK[(mt * 16 + n16) * 72 + quad * 8];
      const bf16x8 a0 = *(const bf16x8*)(ka);
      const bf16x8 a1 = *(const bf16x8*)(ka + 32);
#pragma unroll
      for (int g = 0; g < 4; ++g) {
        f32x4 s = __builtin_amdgcn_mfma_f32_16x16x32_bf16(a0, qf[g][0], zero, 0, 0, 0);
        s       = __builtin_amdgcn_mfma_f32_16x16x32_bf16(a1, qf[g][1], s,    0, 0, 0);
        // lane holds S^T[kv = mt*16+quad*4+r][q = g*16+n16]; kv contiguous in r
        float p0 = __builtin_amdgcn_exp2f(s[0]);
        float p1 = __builtin_amdgcn_exp2f(s[1]);
        float p2 = __builtin_amdgcn_exp2f(s[2]);
        float p3 = __builtin_amdgcn_exp2f(s[3]);
        rsum[g] += (p0 + p1) + (p2 + p3);
        bf16x4 pk = { (bf16_t)p0, (bf16_t)p1, (bf16_t)p2, (bf16_t)p3 };
        *(bf16x4*)(&pw[(g * 16 + n16) * 72 + mt * 16 + quad * 4]) = pk;
      }
    }

    // PV: A = P[q][kv] (A layout, b128 from wave-private sP), B = V-tile rows
    bf16x8 ap[4][2];
#pragma unroll
    for (int g = 0; g < 4; ++g) {
      const bf16_t* pr = &pw[(g * 16 + n16) * 72];
      ap[g][0] = *(const bf16x8*)(pr + quad * 8);
      ap[g][1] = *(const bf16x8*)(pr + 32 + quad * 8);
    }
#pragma unroll
    for (int dt = 0; dt < 8; ++dt) {
      const bf16_t* vb = &sV[(dt * 16 + n16) * 72 + quad * 8];
      const bf16x8 b0 = *(const bf16x8*)(vb);
      const bf16x8 b1 = *(const bf16x8*)(vb + 32);
#pragma unroll
      for (int g = 0; g < 4; ++g) {
        o[g][dt] = __builtin_amdgcn_mfma_f32_16x16x32_bf16(ap[g][0], b0, o[g][dt], 0, 0, 0);
        o[g][dt] = __builtin_amdgcn_mfma_f32_16x16x32_bf16(ap[g][1], b1, o[g][dt], 0, 0, 0);
      }
    }
  }

  // row sums: reduce over quads (lane bits 4,5) -> lane n16 holds sum for
  // q-row g*16+n16
  float lsum[4];
#pragma unroll
  for (int g = 0; g < 4; ++g) {
    float v = rsum[g];
    v += __shfl_xor(v, 16);
    v += __shfl_xor(v, 32);
    lsum[g] = v;
  }

  if (splits > 1) {
    if (quad == 0) {
#pragma unroll
      for (int g = 0; g < 4; ++g)
        Lpart[((long)sp * HEADS + h) * NQ + qbase + g * 16 + n16] = lsum[g];
    }
    bf16_t* ob = Opart + (((long)sp * HEADS + h) * NQ + qbase) * DH;
#pragma unroll
    for (int g = 0; g < 4; ++g)
#pragma unroll
      for (int dt = 0; dt < 8; ++dt)
#pragma unroll
        for (int r = 0; r < 4; ++r)
          ob[(long)(g * 16 + quad * 4 + r) * DH + dt * 16 + n16] = (bf16_t)o[g][dt][r];
  } else {
    float* ob = Out + ((long)h * NQ + qbase) * DH;
#pragma unroll
    for (int g = 0; g < 4; ++g) {
      const float inv = 1.f / lsum[g];
#pragma unroll
      for (int r = 0; r < 4; ++r) {
        const float rinv = __shfl(inv, quad * 4 + r, 16);
#pragma unroll
        for (int dt = 0; dt < 8; ++dt)
          ob[(long)(g * 16 + quad * 4 + r) * DH + dt * 16 + n16] = o[g][dt][r] * rinv;
      }
    }
  }
}

// ---------------------------------------------------------------------------
// combine: Out[hq][d] = (sum_s Opart[s][hq][d]) / (sum_s Lpart[s][hq])
// ---------------------------------------------------------------------------
__global__ __launch_bounds__(256) void combine_kernel(
    const bf16_t* __restrict__ Opart, const float* __restrict__ Lpart,
    float* __restrict__ Out)
{
  const long idx = (long)blockIdx.x * 256 + threadIdx.x;   // 524288 threads
  const int  d8  = (int)(idx & 15);
  const long hq  = idx >> 4;
  float l = 0.f;
  float acc[8];
#pragma unroll
  for (int j = 0; j < 8; ++j) acc[j] = 0.f;
#pragma unroll
  for (int s = 0; s < 4; ++s) {
    l += Lpart[s * (long)(HEADS * NQ) + hq];
    bf16x8 v = *(const bf16x8*)(Opart + (s * (long)(HEADS * NQ) + hq) * DH + d8 * 8);
#pragma unroll
    for (int j = 0; j < 8; ++j) acc[j] += (float)v[j];
  }
  const float inv = 1.f / l;
  f32x4 o0 = { acc[0] * inv, acc[1] * inv, acc[2] * inv, acc[3] * inv };
  f32x4 o1 = { acc[4] * inv, acc[5] * inv, acc[6] * inv, acc[7] * inv };
  float* op = Out + hq * DH + d8 * 8;
  *(f32x4*)(op)     = o0;
  *(f32x4*)(op + 4) = o1;
}

// ---------------------------------------------------------------------------
extern "C" void kernel_launch(void* const* d_in, const int* in_sizes, int n_in,
                              void* d_out, int out_size, void* d_ws, size_t ws_size,
                              hipStream_t stream)
{
  const float* Q = (const float*)d_in[0];
  const float* K = (const float*)d_in[1];
  const float* V = (const float*)d_in[2];
  const float* R = (const float*)d_in[3];
  float* Out = (float*)d_out;

  char* ws = (char*)d_ws;
  bf16_t* Qp = (bf16_t*)(ws);                          //  4 MiB: [16][2048][64]
  bf16_t* Kp = (bf16_t*)(ws + (size_t)(4  << 20));     //  8 MiB: [16][4096][64]
  bf16_t* Vt = (bf16_t*)(ws + (size_t)(12 << 20));     // 16 MiB: [16][128][4096]
  bf16_t* Opart = (bf16_t*)(ws + (size_t)(28 << 20));  // 32 MiB: [4][16][2048][128] bf16
  float*  Lpart = (float*)(ws + (size_t)(60 << 20));   // 2 MiB:  [4][16][2048] fp32

  const size_t need4 = (size_t)(60 << 20) + 4ull * HEADS * NQ * sizeof(float);
  const int splits = (ws_size >= need4) ? 4 : 1;
  const int iters  = NKV / (64 * splits);

  proj_kernel<<<384, 256, 0, stream>>>(Q, K, R, Qp, Kp);
  vtrans_kernel<<<dim3(64, 16), 256, 0, stream>>>(V, Vt);
  flash_kernel<<<splits * 256, 128, 0, stream>>>(Qp, Kp, Vt, Opart, Lpart, Out,
                                                 splits, iters);
  if (splits == 4)
    combine_kernel<<<2048, 256, 0, stream>>>(Opart, Lpart, Out);
}

// Round 4
// 203.649 us; speedup vs baseline: 1.6615x; 1.6615x over previous
//
#include <hip/hip_runtime.h>

#define HEADS 16
#define NQ    2048
#define NKV   4096
#define DH    128
#define PDIM  64

typedef __bf16 bf16_t;
typedef bf16_t bf16x8 __attribute__((ext_vector_type(8)));
typedef bf16_t bf16x4 __attribute__((ext_vector_type(4)));
typedef bf16_t bf16x2 __attribute__((ext_vector_type(2)));
typedef float  f32x4  __attribute__((ext_vector_type(4)));
typedef float  f32x16 __attribute__((ext_vector_type(16)));
typedef int    i32x4  __attribute__((ext_vector_type(4)));

typedef __attribute__((address_space(3))) unsigned int       lds_u32;
typedef __attribute__((address_space(1))) const unsigned int glb_u32;

__device__ __forceinline__ void dma16(const void* g, void* l) {
  __builtin_amdgcn_global_load_lds((glb_u32*)g, (lds_u32*)l, 16, 0, 0);
}

// ---------------------------------------------------------------------------
// proj: rows 0..32767 are Q (scaled by (1/8)*log2e), rows 32768.. are K.
// ---------------------------------------------------------------------------
__global__ __launch_bounds__(256) void proj_kernel(
    const float* __restrict__ Q, const float* __restrict__ K,
    const float* __restrict__ R, bf16_t* __restrict__ Qp, bf16_t* __restrict__ Kp)
{
  __shared__ bf16_t sY[4][16 * 72];
  const int tid  = threadIdx.x;
  const int wave = tid >> 6, lane = tid & 63;
  const int n16  = lane & 15, quad = lane >> 4;

  bf16x8 bfr[4][4];
#pragma unroll
  for (int nt = 0; nt < 4; ++nt) {
    const int n = nt * 16 + n16;
#pragma unroll
    for (int kk = 0; kk < 4; ++kk) {
      const int k0 = kk * 32 + quad * 8;
      bf16x8 b;
#pragma unroll
      for (int j = 0; j < 8; ++j) b[j] = (bf16_t)R[(k0 + j) * PDIM + n];
      bfr[nt][kk] = b;
    }
  }

  const long rowblock = (long)blockIdx.x * 256 + wave * 64;
  const long qrows = (long)HEADS * NQ;

#pragma unroll 1
  for (int t = 0; t < 4; ++t) {
    const long r0 = rowblock + t * 16;
    const float* X; bf16_t* Y; float scale; long xrow;
    if (r0 < qrows) { X = Q; Y = Qp; scale = 0.18033688011112042f; xrow = r0; }   // (1/8)*log2(e)
    else            { X = K; Y = Kp; scale = 1.0f;                 xrow = r0 - qrows; }

    const float* xp = X + (xrow + n16) * DH;
    bf16x8 a[4];
#pragma unroll
    for (int kk = 0; kk < 4; ++kk) {
      const int k0 = kk * 32 + quad * 8;
      f32x4 x0 = *(const f32x4*)(xp + k0);
      f32x4 x1 = *(const f32x4*)(xp + k0 + 4);
      bf16x8 av;
#pragma unroll
      for (int j = 0; j < 4; ++j) { av[j] = (bf16_t)(x0[j] * scale); av[4 + j] = (bf16_t)(x1[j] * scale); }
      a[kk] = av;
    }
    bf16_t* sy = sY[wave];
#pragma unroll
    for (int nt = 0; nt < 4; ++nt) {
      f32x4 acc = {0.f, 0.f, 0.f, 0.f};
#pragma unroll
      for (int kk = 0; kk < 4; ++kk)
        acc = __builtin_amdgcn_mfma_f32_16x16x32_bf16(a[kk], bfr[nt][kk], acc, 0, 0, 0);
#pragma unroll
      for (int r = 0; r < 4; ++r)
        sy[(quad * 4 + r) * 72 + nt * 16 + n16] = (bf16_t)acc[r];
    }
    const int row = lane >> 2, cg = lane & 3;
    bf16x8 w0 = *(const bf16x8*)(&sy[row * 72 + cg * 16]);
    bf16x8 w1 = *(const bf16x8*)(&sy[row * 72 + cg * 16 + 8]);
    *(bf16x8*)(Y + (xrow + row) * PDIM + cg * 16)     = w0;
    *(bf16x8*)(Y + (xrow + row) * PDIM + cg * 16 + 8) = w1;
  }
}

// ---------------------------------------------------------------------------
// V [H][NKV][128] fp32  ->  Vt [H][128][NKV] bf16 (transpose via padded LDS)
// ---------------------------------------------------------------------------
__global__ __launch_bounds__(256) void vtrans_kernel(
    const float* __restrict__ V, bf16_t* __restrict__ Vt)
{
  __shared__ float sF[64 * 129];
  const int tid = threadIdx.x;
  const int h = blockIdx.y, jt = blockIdx.x;
  const float* vp = V + ((long)h * NKV + jt * 64) * DH;
#pragma unroll
  for (int rep = 0; rep < 8; ++rep) {
    const int slot = tid + rep * 256;
    const int j = slot >> 5, c4 = (slot & 31) * 4;
    f32x4 v = *(const f32x4*)(vp + j * DH + c4);
    float* dst = &sF[j * 129 + c4];
    dst[0] = v[0]; dst[1] = v[1]; dst[2] = v[2]; dst[3] = v[3];
  }
  __syncthreads();
  bf16_t* op = Vt + (long)h * DH * NKV + jt * 64;
#pragma unroll
  for (int rep = 0; rep < 4; ++rep) {
    const int slot = tid + rep * 256;
    const int d = slot >> 3, j8 = (slot & 7) * 8;
    bf16x8 w;
#pragma unroll
    for (int jj = 0; jj < 8; ++jj) w[jj] = (bf16_t)sF[(j8 + jj) * 129 + d];
    *(bf16x8*)(op + (long)d * NKV + j8) = w;
  }
}

// ---------------------------------------------------------------------------
// flash v4: fully transposed (S^T = K.Q^T, O^T = V^T.P^T), 32x32x16 MFMA.
// P never touches LDS: S^T C/D regs -> exp2 -> pack bf16 -> shfl_xor(32)
// converts to the P^T B-operand layout in registers. LDS = K/V tiles only
// (24.6 KB), staged via global_load_lds w16 with XOR chunk swizzle
// (phys chunk = c ^ (row&7)) so strided row b128 reads are conflict-free.
// Block = 2 waves x 64 q-rows; split-4 over kv -> 1024 blocks, 4 blocks/CU.
// ---------------------------------------------------------------------------
__global__ __launch_bounds__(128, 2) void flash_kernel(
    const bf16_t* __restrict__ Qp, const bf16_t* __restrict__ Kp,
    const bf16_t* __restrict__ Vt, bf16_t* __restrict__ Opart,
    float* __restrict__ Lpart, float* __restrict__ Out,
    int splits, int iters)
{
  __shared__ char smem[24576];
  bf16_t* sK = (bf16_t*)smem;            // 64 rows x 64, swizzled chunks (8 KB)
  bf16_t* sV = (bf16_t*)(smem + 8192);   // 128 rows x 64, swizzled (16 KB)

  const int tid  = threadIdx.x;
  const int wave = tid >> 6, lane = tid & 63;
  const int l31  = lane & 31, h = lane >> 5;

  const int head = blockIdx.x & 15;      // XCD round-robin -> 2 heads/XCD
  const int qt   = (blockIdx.x >> 4) & 15;
  const int sp   = blockIdx.x >> 8;

  const int qbase = qt * 128 + wave * 64;
  const int kv0   = sp * (64 * iters);

  // persistent Q B-frags: B[k=p][n=q], q = qsub*32+l31, p = k*16 + 8h + j
  bf16x8 qf[2][4];
#pragma unroll
  for (int qsub = 0; qsub < 2; ++qsub)
#pragma unroll
    for (int k = 0; k < 4; ++k)
      qf[qsub][k] = *(const bf16x8*)(Qp + ((long)head * NQ + qbase + qsub * 32 + l31) * PDIM
                                     + k * 16 + h * 8);

  f32x16 o[2][4] = {};          // O^T accum: [qsub][dsub], C layout
  float rsum[2] = {0.f, 0.f};   // per-lane partial row sums

  const bf16_t* kpH = Kp + (long)head * NKV * PDIM;
  const bf16_t* vtH = Vt + (long)head * DH * NKV;

  const int sw = ((lane & 7) ^ ((lane >> 3) & 7)) * 8;  // src-col swizzle (elems)
  const int r8 = lane >> 3;                             // row within 8-row group

  for (int t = 0; t < iters; ++t) {
    const int kvb = kv0 + t * 64;
    __syncthreads();
    if (wave == 0) {
#pragma unroll
      for (int i = 0; i < 8; ++i)
        dma16(kpH + (long)(kvb + i * 8 + r8) * PDIM + sw, smem + i * 1024);
#pragma unroll
      for (int i = 0; i < 4; ++i)
        dma16(vtH + (long)(i * 8 + r8) * NKV + kvb + sw, smem + 8192 + i * 1024);
    } else {
#pragma unroll
      for (int i = 4; i < 16; ++i)
        dma16(vtH + (long)(i * 8 + r8) * NKV + kvb + sw, smem + 8192 + i * 1024);
    }
    __syncthreads();

#pragma unroll
    for (int s = 0; s < 2; ++s) {
      int bfr[2][2][4];   // P^T B-frags: [qsub][cl][4 x b32]
#pragma unroll
      for (int qsub = 0; qsub < 2; ++qsub) {
        // QK: S^T tile [32 kv][32 q], kv row = s*32 + l31
        f32x16 sc = {};
        const int r = s * 32 + l31;
#pragma unroll
        for (int k = 0; k < 4; ++k) {
          const int c = 2 * k + h;
          const bf16x8 a = *(const bf16x8*)(sK + r * 64 + ((c ^ (r & 7)) * 8));
          sc = __builtin_amdgcn_mfma_f32_32x32x16_bf16(a, qf[qsub][k], sc, 0, 0, 0);
        }
        // exp2 (log2-domain, fixed max 0) + pack + per-lane rsum
        int pk[4][2];
#pragma unroll
        for (int rg = 0; rg < 4; ++rg) {
          const float p0 = __builtin_amdgcn_exp2f(sc[rg * 4 + 0]);
          const float p1 = __builtin_amdgcn_exp2f(sc[rg * 4 + 1]);
          const float p2 = __builtin_amdgcn_exp2f(sc[rg * 4 + 2]);
          const float p3 = __builtin_amdgcn_exp2f(sc[rg * 4 + 3]);
          rsum[qsub] += (p0 + p1) + (p2 + p3);
          union { bf16x2 v; int i; } u0, u1;
          u0.v = bf16x2{(bf16_t)p0, (bf16_t)p1};
          u1.v = bf16x2{(bf16_t)p2, (bf16_t)p3};
          pk[rg][0] = u0.i; pk[rg][1] = u1.i;
        }
        // C-layout -> B-layout: j0-3 = half0's pk[2cl+h], j4-7 = half1's
#pragma unroll
        for (int cl = 0; cl < 2; ++cl) {
          const int e00 = __shfl_xor(pk[2 * cl][0], 32);
          const int e01 = __shfl_xor(pk[2 * cl][1], 32);
          const int e10 = __shfl_xor(pk[2 * cl + 1][0], 32);
          const int e11 = __shfl_xor(pk[2 * cl + 1][1], 32);
          bfr[qsub][cl][0] = h ? e10 : pk[2 * cl][0];
          bfr[qsub][cl][1] = h ? e11 : pk[2 * cl][1];
          bfr[qsub][cl][2] = h ? pk[2 * cl + 1][0] : e00;
          bfr[qsub][cl][3] = h ? pk[2 * cl + 1][1] : e01;
        }
      }
      // PV for this s: kv steps c = 2s + cl
#pragma unroll
      for (int dsub = 0; dsub < 4; ++dsub) {
        const int r = dsub * 32 + l31;
#pragma unroll
        for (int cl = 0; cl < 2; ++cl) {
          const int c = 2 * (2 * s + cl) + h;
          const bf16x8 va = *(const bf16x8*)(sV + r * 64 + ((c ^ (r & 7)) * 8));
#pragma unroll
          for (int qsub = 0; qsub < 2; ++qsub) {
            union { i32x4 i; bf16x8 v; } pb;
            pb.i = i32x4{bfr[qsub][cl][0], bfr[qsub][cl][1],
                         bfr[qsub][cl][2], bfr[qsub][cl][3]};
            o[qsub][dsub] = __builtin_amdgcn_mfma_f32_32x32x16_bf16(va, pb.v, o[qsub][dsub], 0, 0, 0);
          }
        }
      }
    }
  }

  // epilogue: transpose O^T -> row-major via wave-private LDS, store coalesced
  __syncthreads();
  bf16_t* myT = (bf16_t*)(smem + wave * 8704);   // 32 rows x 272 B (136 elems)
#pragma unroll
  for (int qsub = 0; qsub < 2; ++qsub) {
    const float lsum = rsum[qsub] + __shfl_xor(rsum[qsub], 32);
    const float scale = (splits > 1) ? 1.0f : (1.0f / lsum);
#pragma unroll
    for (int dsub = 0; dsub < 4; ++dsub)
#pragma unroll
      for (int rg = 0; rg < 4; ++rg) {
        bf16x4 w = { (bf16_t)(o[qsub][dsub][rg * 4 + 0] * scale),
                     (bf16_t)(o[qsub][dsub][rg * 4 + 1] * scale),
                     (bf16_t)(o[qsub][dsub][rg * 4 + 2] * scale),
                     (bf16_t)(o[qsub][dsub][rg * 4 + 3] * scale) };
        *(bf16x4*)(myT + l31 * 136 + dsub * 32 + rg * 8 + h * 4) = w;
      }
    const int qglob = qbase + qsub * 32;
#pragma unroll
    for (int j = 0; j < 8; ++j) {
      const int ql = j * 4 + (lane >> 4);
      bf16x8 v = *(const bf16x8*)(myT + ql * 136 + (lane & 15) * 8);
      if (splits > 1) {
        *(bf16x8*)(Opart + (((long)sp * HEADS + head) * NQ + qglob + ql) * DH + (lane & 15) * 8) = v;
      } else {
        float* op = Out + ((long)head * NQ + qglob + ql) * DH + (lane & 15) * 8;
        f32x4 a = {(float)v[0], (float)v[1], (float)v[2], (float)v[3]};
        f32x4 b = {(float)v[4], (float)v[5], (float)v[6], (float)v[7]};
        *(f32x4*)op = a; *(f32x4*)(op + 4) = b;
      }
    }
    if (splits > 1 && h == 0)
      Lpart[((long)sp * HEADS + head) * NQ + qglob + l31] = lsum;
  }
}

// ---------------------------------------------------------------------------
// combine: Out[hq][d] = (sum_s Opart[s][hq][d]) / (sum_s Lpart[s][hq])
// ---------------------------------------------------------------------------
__global__ __launch_bounds__(256) void combine_kernel(
    const bf16_t* __restrict__ Opart, const float* __restrict__ Lpart,
    float* __restrict__ Out)
{
  const long idx = (long)blockIdx.x * 256 + threadIdx.x;
  const int  d8  = (int)(idx & 15);
  const long hq  = idx >> 4;
  float l = 0.f;
  float acc[8];
#pragma unroll
  for (int j = 0; j < 8; ++j) acc[j] = 0.f;
#pragma unroll
  for (int s = 0; s < 4; ++s) {
    l += Lpart[s * (long)(HEADS * NQ) + hq];
    bf16x8 v = *(const bf16x8*)(Opart + (s * (long)(HEADS * NQ) + hq) * DH + d8 * 8);
#pragma unroll
    for (int j = 0; j < 8; ++j) acc[j] += (float)v[j];
  }
  const float inv = 1.f / l;
  f32x4 o0 = { acc[0] * inv, acc[1] * inv, acc[2] * inv, acc[3] * inv };
  f32x4 o1 = { acc[4] * inv, acc[5] * inv, acc[6] * inv, acc[7] * inv };
  float* op = Out + hq * DH + d8 * 8;
  *(f32x4*)(op)     = o0;
  *(f32x4*)(op + 4) = o1;
}

// ---------------------------------------------------------------------------
extern "C" void kernel_launch(void* const* d_in, const int* in_sizes, int n_in,
                              void* d_out, int out_size, void* d_ws, size_t ws_size,
                              hipStream_t stream)
{
  const float* Q = (const float*)d_in[0];
  const float* K = (const float*)d_in[1];
  const float* V = (const float*)d_in[2];
  const float* R = (const float*)d_in[3];
  float* Out = (float*)d_out;

  char* ws = (char*)d_ws;
  bf16_t* Qp = (bf16_t*)(ws);                          //  4 MiB: [16][2048][64]
  bf16_t* Kp = (bf16_t*)(ws + (size_t)(4  << 20));     //  8 MiB: [16][4096][64]
  bf16_t* Vt = (bf16_t*)(ws + (size_t)(12 << 20));     // 16 MiB: [16][128][4096]
  bf16_t* Opart = (bf16_t*)(ws + (size_t)(28 << 20));  // 32 MiB: [4][16][2048][128]
  float*  Lpart = (float*)(ws + (size_t)(60 << 20));   //  0.5 MiB: [4][16][2048]

  const size_t need4 = (size_t)(60 << 20) + 4ull * HEADS * NQ * sizeof(float);
  const int splits = (ws_size >= need4) ? 4 : 1;
  const int iters  = NKV / (64 * splits);

  proj_kernel<<<384, 256, 0, stream>>>(Q, K, R, Qp, Kp);
  vtrans_kernel<<<dim3(64, 16), 256, 0, stream>>>(V, Vt);
  flash_kernel<<<splits * 256, 128, 0, stream>>>(Qp, Kp, Vt, Opart, Lpart, Out,
                                                 splits, iters);
  if (splits == 4)
    combine_kernel<<<2048, 256, 0, stream>>>(Opart, Lpart, Out);
}